// Round 13
// baseline (848.786 us; speedup 1.0000x reference)
//
#include <hip/hip_runtime.h>
#include <stdint.h>

// IndexFlatIP top-k: sims = Q[512,512] @ X[262144,512]^T, per-row top-10
// indices (desc, ties -> lower index). Output int32 [512,10].
//
// Round 13: all-glds deep pipeline in the proven 2-block/16-wave regime.
//  qprep      : Q fp32 -> f16 RTZ granules, r5-verbatim A-tile order.
//  xprep_tiled: X fp32 -> f16 RTZ granules in B-tile order, r10-verbatim
//               (tile (chunk,nt,kt) = 512 granules, g = koct*128+col).
//  p1         : BM=256 BN=128 BK=32, 512 thr = 8 waves (4M x 2N, wave tile
//               64x64). A: glds, 2-deep LDS (L2 Qsw, 1-step slack).
//               B: glds, 3-deep LDS (HBM Xt4, 2-step slack, ZERO registers).
//               FIFO [B(j):1, A(j):2, B(j+1):1] -> vmcnt(1)/step.
//               Epilogue every 16 steps: full drain, Cs overlays B bufs,
//               3-load pipeline restart. LDS 56KB -> 2 blocks/CU.
//  p2         : pivot filter + exact fp32 rescore (verified rounds 5..12).
#define B_Q   512
#define N_IDX 262144
#define D_DIM 512
#define TOPK  10
#define CAND  6

constexpr int CHUNKS = 256;          // candidate chunks (1024 cols each)
constexpr int NR = N_IDX / CHUNKS;   // 1024
constexpr int BM = 256, BN = 128, BK = 32;
constexpr int NT = NR / BN;          // 8
constexpr int KT = D_DIM / BK;       // 16
constexpr int ITERS = NT * KT;       // 128
constexpr int NCAND = CHUNKS * CAND; // 1536

typedef _Float16 half8 __attribute__((ext_vector_type(8)));
typedef float    f32x4 __attribute__((ext_vector_type(4)));

__device__ __forceinline__ unsigned int pk16(float a, float b)
{
    return __builtin_bit_cast(unsigned int, __builtin_amdgcn_cvt_pkrtz(a, b));
}

__device__ __forceinline__ void glds16(const void* g, char* lds)
{
    __builtin_amdgcn_global_load_lds(
        (const __attribute__((address_space(1))) void*)g,
        (__attribute__((address_space(3))) void*)lds, 16, 0, 0);
}

// ------------------------------------------------------------------ qprep --
// r5-verbatim: tile (qt 0..1, kt 0..15) of 1024 granules; granule =
// slot*256 + row (slot = k-octet 0..3, row 0..255), 16 B each.
__global__ __launch_bounds__(256)
void qprep(const float* __restrict__ Q, uint4* __restrict__ Qsw4)
{
    const int n = blockIdx.x * 256 + threadIdx.x;   // 32768 granules
    const float4 p0 = reinterpret_cast<const float4*>(Q)[n * 2];
    const float4 p1 = reinterpret_cast<const float4*>(Q)[n * 2 + 1];
    uint4 u;
    u.x = pk16(p0.x, p0.y);
    u.y = pk16(p0.z, p0.w);
    u.z = pk16(p1.x, p1.y);
    u.w = pk16(p1.z, p1.w);
    const int kslot = n & 63, rowg = n >> 6;
    const int kt = kslot >> 2, slot = kslot & 3;
    const int qt = rowg >> 8, row = rowg & 255;
    Qsw4[(qt * 16 + kt) * 1024 + slot * 256 + row] = u;
}

// ------------------------------------------------------------ xprep_tiled --
// r10-verbatim. One block per (chunk, nt) panel of 128 X-rows. For each kt,
// each thread emits 2 granules: g = koct*128+col <- X[panel+col][kt*32+koct*8].
__global__ __launch_bounds__(256)
void xprep_tiled(const float* __restrict__ X, uint4* __restrict__ Xt4)
{
    const int chunk = blockIdx.x >> 3, nt = blockIdx.x & 7;
    const int t = threadIdx.x;
    const size_t rowbase = (size_t)(chunk * NR + nt * BN);
    for (int kt = 0; kt < 16; ++kt) {
        uint4* dst = Xt4 + ((size_t)(chunk * 8 + nt) * 16 + kt) * 512;
#pragma unroll
        for (int i = 0; i < 2; ++i) {
            const int g = t + i * 256;            // 0..511
            const int koct = g >> 7, col = g & 127;
            const float* src = X + (rowbase + col) * D_DIM + kt * 32 + koct * 8;
            const float4 p0 = *reinterpret_cast<const float4*>(src);
            const float4 p1 = *reinterpret_cast<const float4*>(src + 4);
            uint4 u;
            u.x = pk16(p0.x, p0.y);
            u.y = pk16(p0.z, p0.w);
            u.z = pk16(p1.x, p1.y);
            u.w = pk16(p1.z, p1.w);
            dst[g] = u;
        }
    }
}

// --------------------------------------------------------------------- p1 --
// Grid 512 (chunk = bx>>1, qt = bx&1), block 512 = 8 waves (wm 0..3, wn 0..1),
// wave tile 64x64, acc 4x4 f32x4.
// LDS 57344: Abuf[2] 16K @0/@16K, Bbuf[3] 8K @32K/@40K/@48K,
//            Cs 256x16 f32 (16K) overlays @32K (only during epilogue pause).
// B-tile index = chunk*128 + j (xprep layout), so B source advances 512
// uint4/step. Per wave per step: 2 A-glds + 1 B-glds.
__global__ __launch_bounds__(512)
void faiss_p1(const uint4* __restrict__ Qsw4, const uint4* __restrict__ Xt4,
              float* __restrict__ cand_v, int* __restrict__ cand_i)
{
    __shared__ __align__(16) char smem[57344];
    float* Cs = (float*)(smem + 32768);

    const int tid  = threadIdx.x;
    const int lane = tid & 63;
    const int w    = tid >> 6;
    const int wm   = w >> 1;       // 0..3 (M quarter, 64 rows)
    const int wn   = w & 1;        // 0..1 (N half, 64 cols)
    const int chunk = blockIdx.x >> 1;
    const int qt    = blockIdx.x & 1;
    const int row0  = qt * 256;

    // A staging: wave w stages granules w*128 + {0..63, 64..127} of (qt,kt).
    const uint4* aTile = Qsw4 + qt * (16 * 1024) + w * 128 + lane;
    const int aDst = (w * 128) * 16;
    // B staging: wave w stages granules w*64 + lane of tile (chunk*128 + j).
    const uint4* bBase = Xt4 + (size_t)(chunk * 128) * 512 + w * 64 + lane;
    const int bDst = (w * 64) * 16;

    // fragment LDS byte offsets (koct = lane>>4), r12-verbatim
    int a_off[4], b_off[4];
#pragma unroll
    for (int i = 0; i < 4; ++i) {
        a_off[i] = ((lane >> 4) * 256 + wm * 64 + i * 16 + (lane & 15)) * 16;
        b_off[i] = ((lane >> 4) * 128 + wn * 64 + i * 16 + (lane & 15)) * 16;
    }

    float topv[CAND]; int topi[CAND];
#pragma unroll
    for (int j = 0; j < CAND; ++j) { topv[j] = -3.0e38f; topi[j] = 0; }

    f32x4 acc[4][4];
#pragma unroll
    for (int mi = 0; mi < 4; ++mi)
#pragma unroll
        for (int ni = 0; ni < 4; ++ni) acc[mi][ni] = (f32x4)0.0f;

    auto issueA = [&](int j) {
        const uint4* s = aTile + (j & 15) * 1024;
        char* d = smem + (j & 1) * 16384;
        glds16(s,      d + aDst);
        glds16(s + 64, d + aDst + 1024);
    };
    auto issueB = [&](int j, int buf) {
        glds16(bBase + (size_t)j * 512, smem + 32768 + buf * 8192 + bDst);
    };
    auto compute = [&](int j, int bufB) {
        const char* ab = smem + (j & 1) * 16384;
        const char* bb = smem + 32768 + bufB * 8192;
        half8 af[4], bf[4];
#pragma unroll
        for (int mi = 0; mi < 4; ++mi)
            af[mi] = *reinterpret_cast<const half8*>(ab + a_off[mi]);
#pragma unroll
        for (int ni = 0; ni < 4; ++ni)
            bf[ni] = *reinterpret_cast<const half8*>(bb + b_off[ni]);
#pragma unroll
        for (int mi = 0; mi < 4; ++mi)
#pragma unroll
            for (int ni = 0; ni < 4; ++ni)
                acc[mi][ni] = __builtin_amdgcn_mfma_f32_16x16x32_f16(
                    af[mi], bf[ni], acc[mi][ni], 0, 0, 0);
    };
    auto epilogue = [&](int nt) {      // r12-verbatim, Cs @ +32768
        const int colbase = chunk * NR + nt * BN;
#pragma unroll
        for (int s = 0; s < 8; ++s) {
            if (wn == (s >> 2)) {
                const int ni = s & 3;
#pragma unroll
                for (int mi = 0; mi < 4; ++mi)
#pragma unroll
                    for (int r = 0; r < 4; ++r) {
                        const int rr = wm * 64 + mi * 16 + (lane >> 4) * 4 + r;
                        Cs[rr * 16 + ((lane & 15) ^ ((rr >> 1) & 15))] = acc[mi][ni][r];
                    }
            }
            asm volatile("s_waitcnt lgkmcnt(0)" ::: "memory");
            __builtin_amdgcn_s_barrier();
            if (tid < 256) {
                const int r = tid;
                const int base = colbase + s * 16;
                for (int c = 0; c < 16; ++c) {
                    const float v = Cs[r * 16 + (c ^ ((r >> 1) & 15))];
                    const int id = base + c;
                    if (v > topv[CAND - 1] ||
                        (v == topv[CAND - 1] && id < topi[CAND - 1])) {
                        topv[CAND - 1] = v; topi[CAND - 1] = id;
#pragma unroll
                        for (int t = CAND - 1; t > 0; --t) {
                            const bool gt = topv[t] > topv[t - 1] ||
                                (topv[t] == topv[t - 1] && topi[t] < topi[t - 1]);
                            if (gt) {
                                const float tv = topv[t]; topv[t] = topv[t - 1]; topv[t - 1] = tv;
                                const int   ti = topi[t]; topi[t] = topi[t - 1]; topi[t - 1] = ti;
                            }
                        }
                    }
                }
            }
            asm volatile("s_waitcnt lgkmcnt(0)" ::: "memory");
            __builtin_amdgcn_s_barrier();
        }
#pragma unroll
        for (int mi = 0; mi < 4; ++mi)
#pragma unroll
            for (int ni = 0; ni < 4; ++ni) acc[mi][ni] = (f32x4)0.0f;
    };

    // prologue: establish FIFO invariant [B(0):1, A(0):2, B(1):1]
    issueB(0, 0);
    __builtin_amdgcn_sched_barrier(0);
    issueA(0);
    __builtin_amdgcn_sched_barrier(0);
    issueB(1, 1);
    __builtin_amdgcn_sched_barrier(0);

    int bufB = 0;   // buf of B(j) = j % 3
    for (int j = 0; j < ITERS; ++j) {
        // entry FIFO: [B(j):1, A(j):2, B(j+1):1] (or [B,A] only at j=127)
        if (j < ITERS - 1)
            asm volatile("s_waitcnt vmcnt(1)" ::: "memory");
        else
            asm volatile("s_waitcnt vmcnt(0)" ::: "memory");
        __builtin_amdgcn_s_barrier();

        if ((j & 15) != 15) {
            // steady: issue A(j+1) then B(j+2) (order preserves FIFO drain)
            issueA(j + 1);
            __builtin_amdgcn_sched_barrier(0);
            if (j + 2 < ITERS) {
                const int b2 = (bufB + 2 == 3) ? 0 : (bufB + 2 > 2 ? bufB - 1 : bufB + 2);
                issueB(j + 2, (bufB + 2) % 3);
                (void)b2;
            }
            __builtin_amdgcn_sched_barrier(0);
            compute(j, bufB);
        } else {
            // epilogue step: compute, drain everything (B(j+1) lands before
            // Cs overlays its buf), epilogue, then 3-load pipeline restart.
            compute(j, bufB);
            asm volatile("s_waitcnt vmcnt(0)" ::: "memory");
            __builtin_amdgcn_s_barrier();
            epilogue(j >> 4);
            if (j + 1 < ITERS) {
                issueB(j + 1, (bufB + 1) % 3);
                __builtin_amdgcn_sched_barrier(0);
                issueA(j + 1);
                __builtin_amdgcn_sched_barrier(0);
                if (j + 2 < ITERS) issueB(j + 2, (bufB + 2) % 3);
                __builtin_amdgcn_sched_barrier(0);
            }
        }
        bufB = (bufB == 2) ? 0 : bufB + 1;
    }

    if (tid < 256) {
        const size_t base = ((size_t)(row0 + tid) * CHUNKS + chunk) * CAND;
#pragma unroll
        for (int j = 0; j < CAND; ++j) {
            cand_v[base + j] = topv[j];
            cand_i[base + j] = topi[j];
        }
    }
}

// --------------------------------------------------------------------- p2 --
// One block per row. Pivot = 24th-largest chunk-head under (v desc, idx asc)
// => pool {e >= pivot} provably contains the f16-top-24 => true top-10.
// Exact fp32 rescore of the pool from original Q,X; deterministic rank.
__global__ __launch_bounds__(256)
void faiss_p2(const float* __restrict__ cand_v, const int* __restrict__ cand_i,
              const float* __restrict__ Q, const float* __restrict__ X,
              int* __restrict__ out)
{
    __shared__ float vs[NCAND];
    __shared__ int   is[NCAND];
    __shared__ float qs[D_DIM];
    __shared__ int   Sidx[NCAND];
    __shared__ float Sval[NCAND];
    __shared__ int   scount;
    __shared__ float pivV;
    __shared__ int   pivI;

    const int row = blockIdx.x, tid = threadIdx.x;

    for (int i = tid; i < NCAND; i += 256) {
        vs[i] = cand_v[(size_t)row * NCAND + i];
        is[i] = cand_i[(size_t)row * NCAND + i];
    }
    if (tid < 128)
        ((float4*)qs)[tid] = ((const float4*)(Q + (size_t)row * D_DIM))[tid];
    if (tid == 0) scount = 0;
    __syncthreads();

    {
        const float h = vs[tid * CAND];
        const int  hid = is[tid * CAND];
        int r = 0;
        for (int j = 0; j < CHUNKS; ++j) {
            const float vj = vs[j * CAND];
            r += (vj > h) || (vj == h && is[j * CAND] < hid);
        }
        if (r == 23) { pivV = h; pivI = hid; }
    }
    __syncthreads();

    const float pv = pivV; const int pi = pivI;
    for (int i = tid; i < NCAND; i += 256) {
        const float v = vs[i]; const int id = is[i];
        if (v > pv || (v == pv && id <= pi)) {
            const int p = atomicAdd(&scount, 1);
            Sidx[p] = id;
        }
    }
    __syncthreads();
    const int nS = scount;

    const int wv = tid >> 6, ln = tid & 63;
    for (int si = wv; si < nS; si += 4) {
        const float* xr = X + (size_t)Sidx[si] * D_DIM + ln * 8;
        const float4 xa = *(const float4*)(xr);
        const float4 xb = *(const float4*)(xr + 4);
        const float* qp = qs + ln * 8;
        float s = 0.0f;
        s = fmaf(qp[0], xa.x, s); s = fmaf(qp[1], xa.y, s);
        s = fmaf(qp[2], xa.z, s); s = fmaf(qp[3], xa.w, s);
        s = fmaf(qp[4], xb.x, s); s = fmaf(qp[5], xb.y, s);
        s = fmaf(qp[6], xb.z, s); s = fmaf(qp[7], xb.w, s);
#pragma unroll
        for (int off = 32; off > 0; off >>= 1)
            s += __shfl_down(s, off);
        if (ln == 0) Sval[si] = s;
    }
    __syncthreads();

    for (int i = tid; i < nS; i += 256) {
        const float v = Sval[i]; const int id = Sidx[i];
        int r = 0;
        for (int j = 0; j < nS; ++j) {
            const float vj = Sval[j];
            r += (vj > v) || (vj == v && Sidx[j] < id);
        }
        if (r < TOPK) out[row * TOPK + r] = id;
    }
}

// ----------------------------------------------------------------- launch --
extern "C" void kernel_launch(void* const* d_in, const int* in_sizes, int n_in,
                              void* d_out, int out_size, void* d_ws, size_t ws_size,
                              hipStream_t stream)
{
    (void)in_sizes; (void)n_in; (void)out_size; (void)ws_size;
    const float* Q = (const float*)d_in[0];
    const float* X = (const float*)d_in[1];
    int* out = (int*)d_out;

    char* ws = (char*)d_ws;
    float* cand_v = (float*)ws;                              // 3.15 MB
    int*   cand_i = (int*)(ws + (size_t)B_Q * NCAND * 4);    // 3.15 MB
    uint4* Qsw4   = (uint4*)(ws + (size_t)B_Q * NCAND * 8);  // 512 KB
    uint4* Xt4    = (uint4*)(ws + (size_t)B_Q * NCAND * 8 + 524288);  // 268 MB

    qprep<<<dim3(128), dim3(256), 0, stream>>>(Q, Qsw4);
    xprep_tiled<<<dim3(2048), dim3(256), 0, stream>>>(X, Xt4);
    faiss_p1<<<dim3(512), dim3(512), 0, stream>>>(Qsw4, Xt4, cand_v, cand_i);
    faiss_p2<<<dim3(B_Q), dim3(256), 0, stream>>>(cand_v, cand_i, Q, X, out);
}